// Round 4
// baseline (425.802 us; speedup 1.0000x reference)
//
#include <hip/hip_runtime.h>
#include <hip/hip_bf16.h>
#include <math.h>

#define D 128
#define S 256
#define ROWS 64
#define LOG_S 5.545177444479562f
#define NSLOT 256
#define SLOT_STRIDE 32   // doubles; 256 B spacing

typedef __attribute__((ext_vector_type(8)))  short    short8;
typedef __attribute__((ext_vector_type(8)))  __bf16   bf16x8;
typedef __attribute__((ext_vector_type(16))) float    floatx16;

__device__ __forceinline__ unsigned short f2bf(float x) {
  __hip_bfloat16 h = __float2bfloat16(x);   // RNE
  return *(unsigned short*)&h;
}

// ---- normalize negatives (eps=1e-8), fold 1/T=10, emit bf16 in the exact
// linear B-fragment order hyper_main's MFMA consumes:
//   neg s = g*32 + c, element k = ki*16 + h*8 + j
//   -> short index ((g*8 + ki)*64 + h*32 + c)*8 + j
__global__ void neg_norm_kernel(const float* __restrict__ emb,
                                const int* __restrict__ negidx,
                                unsigned short* __restrict__ negsw) {
  int s = blockIdx.x;       // 0..S-1
  int L = threadIdx.x;      // 0..63, elements 2L,2L+1
  long idx = (long)negidx[s];
  float2 v = *(const float2*)(emb + idx * D + L * 2);
  float ss = v.x * v.x + v.y * v.y;
#pragma unroll
  for (int off = 1; off < 64; off <<= 1) ss += __shfl_xor(ss, off);
  float sc = 10.0f / fmaxf(sqrtf(ss), 1e-8f);
  int g = s >> 5, c = s & 31;
  int k0 = 2 * L;
  int ki = k0 >> 4, h = (k0 >> 3) & 1, j = k0 & 7;
  ushort2 o = make_ushort2(f2bf(v.x * sc), f2bf(v.y * sc));
  *(ushort2*)(negsw + (size_t)((g * 8 + ki) * 64 + h * 32 + c) * 8 + j) = o;
}

// Staging rewritten for memory-level parallelism: ALL 16 loads (8 own-row +
// 8 pos-row float4) are issued into live arrays before any consumption --
// 256 B in flight per thread vs ~80 B when the compiler serialized under a
// 64-VGPR allocation. Positive-row consumption (ssp/dp) is deferred past the
// barrier so its latency also hides under LDS writes + barrier wait.
__global__ __launch_bounds__(256, 4)
void hyper_main(const float* __restrict__ emb,
                const int* __restrict__ posidx,
                const unsigned short* __restrict__ negsw,
                double* __restrict__ acc,
                int N) {
  __shared__ __align__(16) char smem[16384];
  unsigned short* rows_l = (unsigned short*)smem;

  const int t = threadIdx.x;
  const int lane = t & 63;
  const int w = t >> 6;
  const long rbase = (long)blockIdx.x * ROWS;

  const int r  = t >> 2;
  const int qq = t & 3;
  long n = rbase + r;
  bool valid = (n < (long)N);
  long pi = 0;
  if (valid) pi = (long)posidx[n];

  // ---- issue ALL loads up front ----
  float4 v[8];
  float4 p[8];
#pragma unroll
  for (int k = 0; k < 8; ++k) {
    int c4 = qq + 4 * k;
    v[k] = valid ? *(const float4*)(emb + n * D + c4 * 4)
                 : make_float4(0.f, 0.f, 0.f, 0.f);
  }
#pragma unroll
  for (int k = 0; k < 8; ++k) {
    int c4 = qq + 4 * k;
    p[k] = valid ? *(const float4*)(emb + pi * D + c4 * 4)
                 : make_float4(0.f, 0.f, 0.f, 0.f);
  }

  // ---- consume own row (overlaps pos-row flight) ----
  float ssv = 0.f;
#pragma unroll
  for (int k = 0; k < 8; ++k)
    ssv += v[k].x*v[k].x + v[k].y*v[k].y + v[k].z*v[k].z + v[k].w*v[k].w;
#pragma unroll
  for (int off = 1; off < 4; off <<= 1) ssv += __shfl_xor(ssv, off);

  float inv8 = 1.0f / fmaxf(sqrtf(ssv), 1e-8f);   // cosine-path eps
#pragma unroll
  for (int k = 0; k < 8; ++k) {
    int c4 = qq + 4 * k;
    int u = (c4 >> 1) ^ (r & 15);
    ushort4 o = make_ushort4(f2bf(v[k].x*inv8), f2bf(v[k].y*inv8),
                             f2bf(v[k].z*inv8), f2bf(v[k].w*inv8));
    *(ushort4*)&rows_l[r * 128 + u * 8 + (c4 & 1) * 4] = o;
  }

  __syncthreads();   // rows staged

  // ---- consume pos row AFTER the barrier: its flight hid under the LDS
  //      writes + barrier wait of the slowest wave ----
  float ssp = 0.f, dp = 0.f;
#pragma unroll
  for (int k = 0; k < 8; ++k) {
    ssp += p[k].x*p[k].x + p[k].y*p[k].y + p[k].z*p[k].z + p[k].w*p[k].w;
    dp  += v[k].x*p[k].x + v[k].y*p[k].y + v[k].z*p[k].z + v[k].w*p[k].w;
  }
#pragma unroll
  for (int off = 1; off < 4; off <<= 1) {
    ssp += __shfl_xor(ssp, off);
    dp  += __shfl_xor(dp,  off);
  }
  float possum = 0.f;
  if (qq == 0 && valid) {
    float invv = 1.0f / fmaxf(sqrtf(ssv), 1e-12f);  // F.normalize eps
    float invp = 1.0f / fmaxf(sqrtf(ssp), 1e-12f);
    possum = dp * invv * invp * 10.0f;
  }

  // ---- MFMA over negatives: A from LDS rows, B straight from global
  //      (L2-hot). Plain exp-sum (|logit|<=10 -> no overflow). ----
  const int q   = lane >> 5;
  const int ln  = lane & 31;
  const int tr  = w >> 1;
  const int chh = w & 1;
  const int arow = tr * 32 + ln;

  float se[16];
#pragma unroll
  for (int i = 0; i < 16; ++i) se[i] = 0.f;

#pragma unroll 1
  for (int c = 0; c < 2; ++c) {
    const int gA = chh * 4 + c * 2;      // this pass: groups gA, gA+1
    floatx16 acc0 = {};
    floatx16 acc1 = {};
#pragma unroll
    for (int ki = 0; ki < 8; ++ki) {
      int lu = ki * 2 + q;
      short8 a  = *(const short8*)&rows_l[arow * 128 + (lu ^ (arow & 15)) * 8];
      short8 b0 = *(const short8*)(negsw + (size_t)(((gA    ) * 8 + ki) * 64 + lane) * 8);
      short8 b1 = *(const short8*)(negsw + (size_t)(((gA + 1) * 8 + ki) * 64 + lane) * 8);
      acc0 = __builtin_amdgcn_mfma_f32_32x32x16_bf16(
          __builtin_bit_cast(bf16x8, a), __builtin_bit_cast(bf16x8, b0), acc0, 0, 0, 0);
      acc1 = __builtin_amdgcn_mfma_f32_32x32x16_bf16(
          __builtin_bit_cast(bf16x8, a), __builtin_bit_cast(bf16x8, b1), acc1, 0, 0, 0);
    }
#pragma unroll
    for (int rg = 0; rg < 16; ++rg)
      se[rg] += __expf(acc0[rg]) + __expf(acc1[rg]);
  }

  // ---- combine exp-sums across the 32 lanes of each half-wave ----
#pragma unroll
  for (int rg = 0; rg < 16; ++rg) {
    float sv = se[rg];
#pragma unroll
    for (int off = 1; off < 32; off <<= 1) sv += __shfl_xor(sv, off);
    se[rg] = sv;
  }

  // ---- merge the two column-half waves via LDS (reuse rows region) ----
  __syncthreads();
  float* sebuf = (float*)smem;   // [64 rows][2 halves]
  if (ln == 0) {
#pragma unroll
    for (int rg = 0; rg < 16; ++rg) {
      int rr = tr * 32 + (rg & 3) + 8 * (rg >> 2) + 4 * q;
      sebuf[rr * 2 + chh] = se[rg];
    }
  }
  __syncthreads();

  float negterm = 0.f;
  if (t < 64) {
    long n2 = rbase + t;
    if (n2 < (long)N)
      negterm = __logf(sebuf[t * 2] + sebuf[t * 2 + 1]) - LOG_S;
  }

  // ---- block reduce -> one double atomic into a spread slot ----
  float local = negterm - possum;
#pragma unroll
  for (int off = 1; off < 64; off <<= 1) local += __shfl_xor(local, off);
  float* red = (float*)(smem + 2048);
  if (lane == 0) red[w] = local;
  __syncthreads();
  if (t == 0) {
    double tot = (double)red[0] + (double)red[1] +
                 (double)red[2] + (double)red[3];
    atomicAdd(acc + (blockIdx.x & (NSLOT - 1)) * SLOT_STRIDE, tot);
  }
}

__global__ void finish_kernel(const double* __restrict__ acc,
                              float* __restrict__ out, int N) {
  double tot = 0.0;
  for (int i = 0; i < NSLOT; ++i) tot += acc[i * SLOT_STRIDE];
  out[0] = (float)(tot / (double)N);
}

extern "C" void kernel_launch(void* const* d_in, const int* in_sizes, int n_in,
                              void* d_out, int out_size, void* d_ws, size_t ws_size,
                              hipStream_t stream) {
  const float* emb  = (const float*)d_in[0];
  const int* posidx = (const int*)d_in[1];
  const int* negidx = (const int*)d_in[2];
  int N = in_sizes[1];

  double* acc = (double*)d_ws;                                   // 64 KB slots
  unsigned short* negsw = (unsigned short*)((char*)d_ws + 65536); // 64 KB negs

  hipMemsetAsync(d_ws, 0, 65536, stream);
  neg_norm_kernel<<<S, 64, 0, stream>>>(emb, negidx, negsw);
  int grid = (N + ROWS - 1) / ROWS;
  hyper_main<<<grid, 256, 0, stream>>>(emb, posidx, negsw, acc, N);
  finish_kernel<<<1, 1, 0, stream>>>(acc, (float*)d_out, N);
}

// Round 5
// 417.043 us; speedup vs baseline: 1.0210x; 1.0210x over previous
//
#include <hip/hip_runtime.h>
#include <hip/hip_bf16.h>
#include <math.h>

#define D 128
#define S 256
#define ROWS 64
#define LOG_S 5.545177444479562f
#define NSLOT 256
#define SLOT_STRIDE 32   // doubles; 256 B spacing

typedef __attribute__((ext_vector_type(8)))  short    short8;
typedef __attribute__((ext_vector_type(8)))  __bf16   bf16x8;
typedef __attribute__((ext_vector_type(16))) float    floatx16;

__device__ __forceinline__ unsigned short f2bf(float x) {
  __hip_bfloat16 h = __float2bfloat16(x);   // RNE
  return *(unsigned short*)&h;
}

// ---- normalize negatives (eps=1e-8), fold 1/T=10, emit bf16 in the exact
// linear B-fragment order hyper_main's MFMA consumes:
//   neg s = g*32 + c, element k = ki*16 + h*8 + j
//   -> short index ((g*8 + ki)*64 + h*32 + c)*8 + j
__global__ void neg_norm_kernel(const float* __restrict__ emb,
                                const int* __restrict__ negidx,
                                unsigned short* __restrict__ negsw) {
  int s = blockIdx.x;       // 0..S-1
  int L = threadIdx.x;      // 0..63, elements 2L,2L+1
  long idx = (long)negidx[s];
  float2 v = *(const float2*)(emb + idx * D + L * 2);
  float ss = v.x * v.x + v.y * v.y;
#pragma unroll
  for (int off = 1; off < 64; off <<= 1) ss += __shfl_xor(ss, off);
  float sc = 10.0f / fmaxf(sqrtf(ss), 1e-8f);
  int g = s >> 5, c = s & 31;
  int k0 = 2 * L;
  int ki = k0 >> 4, h = (k0 >> 3) & 1, j = k0 & 7;
  ushort2 o = make_ushort2(f2bf(v.x * sc), f2bf(v.y * sc));
  *(ushort2*)(negsw + (size_t)((g * 8 + ki) * 64 + h * 32 + c) * 8 + j) = o;
}

// Every prior round was capped at ~1.5 TB/s by load serialization: the
// compiler pinned VGPR=64 and issued gathers in ~4-load batches (~1.7 KB
// in flight per CU vs the ~9 KB Little's law needs for 6.3 TB/s).
// This version PINS deep load batches with sched_barrier(0) at both load
// sites and raises the VGPR budget via launch_bounds(256,3).
__global__ __launch_bounds__(256, 3)
void hyper_main(const float* __restrict__ emb,
                const int* __restrict__ posidx,
                const unsigned short* __restrict__ negsw,
                double* __restrict__ acc,
                int N) {
  __shared__ __align__(16) char smem[16384];
  unsigned short* rows_l = (unsigned short*)smem;

  const int t = threadIdx.x;
  const int lane = t & 63;
  const int w = t >> 6;
  const long rbase = (long)blockIdx.x * ROWS;

  const int r  = t >> 2;
  const int qq = t & 3;
  long n = rbase + r;
  bool valid = (n < (long)N);
  long pi = 0;
  if (valid) pi = (long)posidx[n];

  // ---- issue ALL 16 staging loads, then PIN them above everything ----
  float4 v[8];
  float4 p[8];
  const float* vbase = emb + n * D + qq * 4;
  const float* pbase = emb + pi * D + qq * 4;
#pragma unroll
  for (int k = 0; k < 8; ++k)
    v[k] = valid ? *(const float4*)(vbase + 16 * k)
                 : make_float4(0.f, 0.f, 0.f, 0.f);
#pragma unroll
  for (int k = 0; k < 8; ++k)
    p[k] = valid ? *(const float4*)(pbase + 16 * k)
                 : make_float4(0.f, 0.f, 0.f, 0.f);
  __builtin_amdgcn_sched_barrier(0);   // loads may not sink below this point

  // ---- consume own row ----
  float ssv = 0.f;
#pragma unroll
  for (int k = 0; k < 8; ++k)
    ssv += v[k].x*v[k].x + v[k].y*v[k].y + v[k].z*v[k].z + v[k].w*v[k].w;
#pragma unroll
  for (int off = 1; off < 4; off <<= 1) ssv += __shfl_xor(ssv, off);

  float inv8 = 1.0f / fmaxf(sqrtf(ssv), 1e-8f);   // cosine-path eps
#pragma unroll
  for (int k = 0; k < 8; ++k) {
    int c4 = qq + 4 * k;
    int u = (c4 >> 1) ^ (r & 15);
    ushort4 o = make_ushort4(f2bf(v[k].x*inv8), f2bf(v[k].y*inv8),
                             f2bf(v[k].z*inv8), f2bf(v[k].w*inv8));
    *(ushort4*)&rows_l[r * 128 + u * 8 + (c4 & 1) * 4] = o;
  }

  // ---- consume pos row BEFORE the barrier (latency already hidden under
  //      the own-row consume chain); v,p die here -> regs free for MFMA ----
  float ssp = 0.f, dp = 0.f;
#pragma unroll
  for (int k = 0; k < 8; ++k) {
    ssp += p[k].x*p[k].x + p[k].y*p[k].y + p[k].z*p[k].z + p[k].w*p[k].w;
    dp  += v[k].x*p[k].x + v[k].y*p[k].y + v[k].z*p[k].z + v[k].w*p[k].w;
  }
#pragma unroll
  for (int off = 1; off < 4; off <<= 1) {
    ssp += __shfl_xor(ssp, off);
    dp  += __shfl_xor(dp,  off);
  }
  float possum = 0.f;
  if (qq == 0 && valid) {
    float invv = 1.0f / fmaxf(sqrtf(ssv), 1e-12f);  // F.normalize eps
    float invp = 1.0f / fmaxf(sqrtf(ssp), 1e-12f);
    possum = dp * invv * invp * 10.0f;
  }

  __syncthreads();   // rows staged

  // ---- MFMA over negatives: A from LDS rows, B from L2-hot negsw.
  //      Per pass: issue ALL 16 B-fragment loads (pinned), then 16 MFMAs.
  //      One L2 round-trip per pass instead of eight. ----
  const int q   = lane >> 5;
  const int ln  = lane & 31;
  const int tr  = w >> 1;
  const int chh = w & 1;
  const int arow = tr * 32 + ln;

  float se[16];
#pragma unroll
  for (int i = 0; i < 16; ++i) se[i] = 0.f;

#pragma unroll 1
  for (int c = 0; c < 2; ++c) {
    const int gA = chh * 4 + c * 2;      // this pass: groups gA, gA+1
    short8 bb0[8];
    short8 bb1[8];
#pragma unroll
    for (int ki = 0; ki < 8; ++ki) {
      bb0[ki] = *(const short8*)(negsw + (size_t)(((gA    ) * 8 + ki) * 64 + lane) * 8);
      bb1[ki] = *(const short8*)(negsw + (size_t)(((gA + 1) * 8 + ki) * 64 + lane) * 8);
    }
    __builtin_amdgcn_sched_barrier(0);   // all 16 B loads issued before MFMAs

    floatx16 acc0 = {};
    floatx16 acc1 = {};
#pragma unroll
    for (int ki = 0; ki < 8; ++ki) {
      int lu = ki * 2 + q;
      short8 a = *(const short8*)&rows_l[arow * 128 + (lu ^ (arow & 15)) * 8];
      acc0 = __builtin_amdgcn_mfma_f32_32x32x16_bf16(
          __builtin_bit_cast(bf16x8, a), __builtin_bit_cast(bf16x8, bb0[ki]), acc0, 0, 0, 0);
      acc1 = __builtin_amdgcn_mfma_f32_32x32x16_bf16(
          __builtin_bit_cast(bf16x8, a), __builtin_bit_cast(bf16x8, bb1[ki]), acc1, 0, 0, 0);
    }
#pragma unroll
    for (int rg = 0; rg < 16; ++rg)
      se[rg] += __expf(acc0[rg]) + __expf(acc1[rg]);
  }

  // ---- combine exp-sums across the 32 lanes of each half-wave ----
#pragma unroll
  for (int rg = 0; rg < 16; ++rg) {
    float sv = se[rg];
#pragma unroll
    for (int off = 1; off < 32; off <<= 1) sv += __shfl_xor(sv, off);
    se[rg] = sv;
  }

  // ---- merge the two column-half waves via LDS (reuse rows region) ----
  __syncthreads();
  float* sebuf = (float*)smem;   // [64 rows][2 halves]
  if (ln == 0) {
#pragma unroll
    for (int rg = 0; rg < 16; ++rg) {
      int rr = tr * 32 + (rg & 3) + 8 * (rg >> 2) + 4 * q;
      sebuf[rr * 2 + chh] = se[rg];
    }
  }
  __syncthreads();

  float negterm = 0.f;
  if (t < 64) {
    long n2 = rbase + t;
    if (n2 < (long)N)
      negterm = __logf(sebuf[t * 2] + sebuf[t * 2 + 1]) - LOG_S;
  }

  // ---- block reduce -> one double atomic into a spread slot ----
  float local = negterm - possum;
#pragma unroll
  for (int off = 1; off < 64; off <<= 1) local += __shfl_xor(local, off);
  float* red = (float*)(smem + 2048);
  if (lane == 0) red[w] = local;
  __syncthreads();
  if (t == 0) {
    double tot = (double)red[0] + (double)red[1] +
                 (double)red[2] + (double)red[3];
    atomicAdd(acc + (blockIdx.x & (NSLOT - 1)) * SLOT_STRIDE, tot);
  }
}

__global__ void finish_kernel(const double* __restrict__ acc,
                              float* __restrict__ out, int N) {
  double tot = 0.0;
  for (int i = 0; i < NSLOT; ++i) tot += acc[i * SLOT_STRIDE];
  out[0] = (float)(tot / (double)N);
}

extern "C" void kernel_launch(void* const* d_in, const int* in_sizes, int n_in,
                              void* d_out, int out_size, void* d_ws, size_t ws_size,
                              hipStream_t stream) {
  const float* emb  = (const float*)d_in[0];
  const int* posidx = (const int*)d_in[1];
  const int* negidx = (const int*)d_in[2];
  int N = in_sizes[1];

  double* acc = (double*)d_ws;                                   // 64 KB slots
  unsigned short* negsw = (unsigned short*)((char*)d_ws + 65536); // 64 KB negs

  hipMemsetAsync(d_ws, 0, 65536, stream);
  neg_norm_kernel<<<S, 64, 0, stream>>>(emb, negidx, negsw);
  int grid = (N + ROWS - 1) / ROWS;
  hyper_main<<<grid, 256, 0, stream>>>(emb, posidx, negsw, acc, N);
  finish_kernel<<<1, 1, 0, stream>>>(acc, (float*)d_out, N);
}